// Round 13
// baseline (8086.282 us; speedup 1.0000x reference)
//
#include <hip/hip_runtime.h>

typedef _Float16 f16x8 __attribute__((ext_vector_type(8)));
typedef float    f32x4 __attribute__((ext_vector_type(4)));
typedef unsigned long long u64;
typedef u64 u64x2 __attribute__((ext_vector_type(2)));

constexpr int BATCH = 1024;
constexpr int HDIM  = 512;
constexpr int TENC  = 512;
constexpr int PRED  = 48;
constexpr int STEPS = TENC + PRED - 1;   // 559 cell steps; loop runs 560 (last = fc only)
constexpr int NG    = 64;                // groups (16 batches each)
constexpr int GB    = 16;                // batches per group = one MFMA m-tile
constexpr int UBU   = 64;                // units per block (8 waves x 16, 2 gate-sets)
constexpr int HB_OFF = 32768;

// R23: TLP instead of software phase-interleave. R22 (gate-split, 2652us)
// cut VGPR to 120 but the grid (256 blocks = 1 block/CU) capped occupancy
// at 8 waves/CU -- grid-limited, not register-limited. Now each block runs
// ONE group (512 blocks, 2 blocks/CU, __launch_bounds__(512,4) -> 16
// waves/CU): while one block sleeps in the canary loop (s_sleep frees the
// SIMD), the co-resident block computes. This covers exchange RT, barrier
// skew, AND LDS latency -- the A/B software interleave only covered the
// first. Protocol unchanged: in-band tags (R7/8), canary validate (R15),
// fenced waits rule #18 (R18), liveness pins (R21), gate-split epilogue
// (R22). Boundary wait is plain vmcnt(0): own-store ACK is dominated by
// the peer-store wait that the step must do anyway.
constexpr u64 TAG_MASK = 0x0001000100010001ull;
__device__ __forceinline__ u64 tag_of(int t) {
  return ((u64)(t & 1) | ((u64)((t >> 1) & 1) << 16)) * 0x0000000100000001ull;
}

__global__ void init_kernel(int* wsi) {
  int idx = blockIdx.x * blockDim.x + threadIdx.x;
  int stride = gridDim.x * blockDim.x;
  const int nws = (HB_OFF + BATCH * HDIM * 2) / 4;  // hbuf[0] = h_0 = 0 (tag 00)
  for (int i = idx; i < nws; i += stride) wsi[i] = 0;
  // hbuf[1] stays poison -> tag-invalid until written
}

static __device__ __forceinline__ f16x8 load16_llc(const _Float16* p) {
  f16x8 v;
  asm volatile("global_load_dwordx4 %0, %1, off sc0 sc1"
               : "=v"(v) : "v"((u64)p) : "memory");
  return v;
}
static __device__ __forceinline__ unsigned loadc_llc(const void* p) {
  unsigned v;   // 4B canary: in-band tag probe
  asm volatile("global_load_dword %0, %1, off sc0 sc1"
               : "=v"(v) : "v"((u64)p) : "memory");
  return v;
}
static __device__ __forceinline__ float loadx(const float* p) {
  float v;   // plain cached load via asm so compiler never drains our pipeline
  asm volatile("global_load_dword %0, %1, off"
               : "=v"(v) : "v"((u64)p) : "memory");
  return v;
}
// s_sleep needs a literal operand: 4-step constant backoff ladder.
static __device__ __forceinline__ void sleep_bk(int stage) {
  if (stage == 0)      __builtin_amdgcn_s_sleep(1);
  else if (stage == 1) __builtin_amdgcn_s_sleep(2);
  else if (stage == 2) __builtin_amdgcn_s_sleep(4);
  else                 __builtin_amdgcn_s_sleep(8);
}
// fenced waits (rule #18): checks gating on a wait must not hoist above it.
static __device__ __forceinline__ void wait_vm0_fenced() {
  asm volatile("s_waitcnt vmcnt(0)" ::: "memory");
  __builtin_amdgcn_sched_barrier(0);
}
// raw barrier: LDS-drain + s_barrier, NO vmcnt drain (stores/loads in flight)
static __device__ __forceinline__ void lds_barrier() {
  asm volatile("s_waitcnt lgkmcnt(0)" ::: "memory");
  __builtin_amdgcn_s_barrier();
}

__global__ __launch_bounds__(512, 4) void lstm_persist(
    const float* __restrict__ x,
    const float* __restrict__ w_ih,
    const float* __restrict__ w_hh,
    const float* __restrict__ b_ih,
    const float* __restrict__ b_hh,
    const float* __restrict__ w_fc,
    const float* __restrict__ b_fc,
    float* __restrict__ out,          // [1024][48] fp32
    _Float16* __restrict__ hbuf)      // [2][1024][512] fp16 ping-pong, tagged
{
  const int bid  = blockIdx.x;        // 512 blocks: 64 groups x 8 unit-slices
  const int grp  = bid >> 3;          // group (0..63)
  const int ub   = bid & 7;
  const int tid  = threadIdx.x;       // 0..511
  const int wid  = tid >> 6;          // 0..7
  const int ws   = wid >> 2;          // waveset 0: gates i,f; 1: gates g,o
  const int wq   = wid & 3;           // wave-in-set -> 16-unit column slice
  const int lane = tid & 63;
  const int quad = lane >> 4;
  const int lcol = lane & 15;
  const int b0   = grp * GB;
  const int myu  = ub * UBU + wq * 16 + lcol;   // GEMM-layout unit
  const int cb   = tid >> 5;          // epilogue cell batch (0..15)
  const int cu   = (tid * 2) & 63;    // epilogue cell unit pair base (even)

  __shared__ __align__(16) _Float16 hs[GB][520];     // 16.6 KB
  __shared__ __align__(16) _Float16 wz[520];         // fp16 w_fc + zero pad
  __shared__ float gl[4][GB][68];                    // 17.4 KB gate exchange (padded)
  __shared__ float xls[GB];                          // dec: fc(h) per batch
  __shared__ float outs[GB][PRED];                   // 3 KB predictions

  wz[tid] = (tid < 512) ? (_Float16)w_fc[tid] : (_Float16)0.f;
  if (tid < 8) wz[512 + tid] = (_Float16)0.f;

  // ---- GEMM-layout weights: 2 gates per thread (gate-split, R22) ----
  f16x8 wf2[2][16];
#pragma unroll
  for (int ntl = 0; ntl < 2; ++ntl) {
    const int j = (2 * ws + ntl) * HDIM + myu;
#pragma unroll
    for (int kc = 0; kc < 16; ++kc) {
      const float* s = w_hh + (size_t)j * HDIM + kc * 32 + quad * 8;
      f16x8 v;
#pragma unroll
      for (int i = 0; i < 8; ++i) v[i] = (_Float16)s[i];
      wf2[ntl][kc] = v;
    }
  }
  // ---- cell-layout weights for the epilogue (2 cells x 4 gates) ----
  float wihc[2][4], biasc[2][4];
#pragma unroll
  for (int e = 0; e < 2; ++e)
#pragma unroll
    for (int g = 0; g < 4; ++g) {
      const int j = g * HDIM + ub * UBU + cu + e;
      wihc[e][g]  = w_ih[j];
      biasc[e][g] = b_ih[j] + b_hh[j];
    }
  const float bfc = b_fc[0];

  float cst2[2] = {0.f, 0.f};
  f16x8 tA[2];
  float xA;

  // staging: 1024 16B-chunks, 512 threads -> 2 each (c = i*512+tid)
  auto issue2 = [&](f16x8* tr, const _Float16* base) {
#pragma unroll
    for (int i = 0; i < 2; ++i) {
      const int c = i * 512 + tid;
      tr[i] = load16_llc(base + (size_t)(c >> 6) * HDIM + (c & 63) * 8);
    }
  };
  auto validate2 = [&](f16x8* tr, const _Float16* base, u64 expect) {
    const unsigned exp32 = (unsigned)expect & 0x00010001u;
    unsigned stale = 0;
#pragma unroll
    for (int i = 0; i < 2; ++i) {
      u64x2 w2 = __builtin_bit_cast(u64x2, tr[i]);
      if (((w2[0] & TAG_MASK) != expect) || ((w2[1] & TAG_MASK) != expect))
        stale |= 1u << i;
    }
    int slp = 0;
    while (stale) {
      sleep_bk(slp);             // s_sleep frees the SIMD for the co-resident block
      if (slp < 3) ++slp;
      unsigned cv[2];
#pragma unroll
      for (int i = 0; i < 2; ++i)
        if (stale & (1u << i)) {
          const int c = i * 512 + tid;
          cv[i] = loadc_llc(base + (size_t)(c >> 6) * HDIM + (c & 63) * 8);
        }
      wait_vm0_fenced();          // canary values readable only after this
      unsigned rdy = 0;
#pragma unroll
      for (int i = 0; i < 2; ++i)
        if ((stale & (1u << i)) && ((cv[i] & 0x00010001u) == exp32))
          rdy |= 1u << i;
      if (!rdy) continue;
#pragma unroll
      for (int i = 0; i < 2; ++i)
        if (rdy & (1u << i)) {
          const int c = i * 512 + tid;
          tr[i] = load16_llc(base + (size_t)(c >> 6) * HDIM + (c & 63) * 8);
        }
      wait_vm0_fenced();          // reloads readable only after this
#pragma unroll
      for (int i = 0; i < 2; ++i)
        if (rdy & (1u << i)) {
          u64x2 w2 = __builtin_bit_cast(u64x2, tr[i]);
          if (((w2[0] & TAG_MASK) == expect) && ((w2[1] & TAG_MASK) == expect))
            stale &= ~(1u << i);
        }
    }
  };
  auto stage2 = [&](f16x8* tr) {
#pragma unroll
    for (int i = 0; i < 2; ++i) {
      const int c = i * 512 + tid;
      *reinterpret_cast<f16x8*>(&hs[c >> 6][(c & 63) * 8]) = tr[i];
    }
  };
  auto gemm2 = [&](f32x4* acc, f32x4& accF, bool dec) {
#pragma unroll
    for (int kc = 0; kc < 16; ++kc) {
      const f16x8 a = *reinterpret_cast<const f16x8*>(&hs[lcol][kc * 32 + quad * 8]);
      acc[0] = __builtin_amdgcn_mfma_f32_16x16x32_f16(a, wf2[0][kc], acc[0], 0, 0, 0);
      acc[1] = __builtin_amdgcn_mfma_f32_16x16x32_f16(a, wf2[1][kc], acc[1], 0, 0, 0);
      if (dec && ws == 0) {   // fc computed redundantly per ws0 wave (full K)
        const f16x8 wv = *reinterpret_cast<const f16x8*>(
            &wz[(lcol == 0) ? (kc * 32 + quad * 8) : 512]);
        accF = __builtin_amdgcn_mfma_f32_16x16x32_f16(a, wv, accF, 0, 0, 0);
      }
    }
  };
  // gates -> LDS -> barrier -> per-cell epilogue (2 cells/thread) -> h store
  auto phase_epi = [&](f32x4* acc, f32x4& accF, float xreg,
                       int t, _Float16* hnxt, bool dec) {
#pragma unroll
    for (int ntl = 0; ntl < 2; ++ntl)
#pragma unroll
      for (int r = 0; r < 4; ++r)
        gl[2 * ws + ntl][quad * 4 + r][wq * 16 + lcol] = acc[ntl][r];
    if (dec && wid == 0 && lcol == 0) {   // lanes 0,16,32,48 of wave 0
#pragma unroll
      for (int r = 0; r < 4; ++r) xls[quad * 4 + r] = accF[r] + bfc;
    }
    lds_barrier();
    if (dec && ub == 0 && (tid & 31) == 0)
      outs[cb][t - TENC] = xls[cb];
    const float xt = dec ? xls[cb] : xreg;
    if (t < STEPS) {
      const unsigned tag32 = (unsigned)tag_of(t + 1);
      unsigned v32 = 0;
#pragma unroll
      for (int e = 0; e < 2; ++e) {
        const int u = cu + e;
        const float gi = gl[0][cb][u] + xt * wihc[e][0] + biasc[e][0];
        const float gf = gl[1][cb][u] + xt * wihc[e][1] + biasc[e][1];
        const float gg = gl[2][cb][u] + xt * wihc[e][2] + biasc[e][2];
        const float go = gl[3][cb][u] + xt * wihc[e][3] + biasc[e][3];
        const float si = 1.f / (1.f + __expf(-gi));
        const float sf = 1.f / (1.f + __expf(-gf));
        const float so = 1.f / (1.f + __expf(-go));
        const float tg = 1.f - 2.f / (1.f + __expf(2.f * gg));
        const float cn = sf * cst2[e] + si * tg;
        cst2[e] = cn;
        const float tc = 1.f - 2.f / (1.f + __expf(2.f * cn));
        const unsigned short hb =
            __builtin_bit_cast(unsigned short, (_Float16)(so * tc));
        v32 |= ((unsigned)hb) << (16 * e);
      }
      v32 = (v32 & ~0x00010001u) | tag32;
      unsigned* dst = (unsigned*)(hnxt + (size_t)(b0 + cb) * HDIM
                                  + ub * UBU + cu);
      __hip_atomic_store(dst, v32, __ATOMIC_RELAXED, __HIP_MEMORY_SCOPE_AGENT);
    }
  };

  lds_barrier();   // wz visible

  // ---- prologue: h(0) + x(0) in flight (2h + 1x per thread) ----
  issue2(tA, hbuf + (size_t)b0 * HDIM);
  xA = loadx(x + (size_t)(b0 + cb) * TENC + 0);

  for (int t = 0; t <= STEPS; ++t) {
    const _Float16* hcur = hbuf + (size_t)(t & 1) * BATCH * HDIM;
    _Float16*       hnxt = hbuf + (size_t)((t + 1) & 1) * BATCH * HDIM;
    const u64 expect = tag_of(t);
    const bool dec = (t >= TENC);

    wait_vm0_fenced();             // h(t)+x(t) prefetch (+ last step's store)
    asm volatile("" :: "v"(xA));   // liveness pin (R21-proven)
    validate2(tA, hcur + (size_t)b0 * HDIM, expect);
    stage2(tA);
    lds_barrier();

    f32x4 acc[2], accF;
    acc[0] = (f32x4){0.f, 0.f, 0.f, 0.f};
    acc[1] = (f32x4){0.f, 0.f, 0.f, 0.f};
    accF = (f32x4){0.f, 0.f, 0.f, 0.f};
    gemm2(acc, accF, dec);
    phase_epi(acc, accF, xA, t, hnxt, dec);

    if (t < STEPS) {               // prefetch h(t+1) + x(t+1) (dummy col in decode)
      issue2(tA, hnxt + (size_t)b0 * HDIM);
      xA = loadx(x + (size_t)(b0 + cb) * TENC
                 + (t + 1 < TENC ? t + 1 : TENC - 1));
    }
  }

  // flush buffered predictions
  lds_barrier();
  if (ub == 0) {
    for (int k = tid; k < GB * PRED; k += 512)
      out[(size_t)(b0 + k / PRED) * PRED + (k % PRED)] = outs[k / PRED][k % PRED];
  }
}

extern "C" void kernel_launch(void* const* d_in, const int* in_sizes, int n_in,
                              void* d_out, int out_size, void* d_ws, size_t ws_size,
                              hipStream_t stream) {
  const float* x    = (const float*)d_in[0];
  const float* w_ih = (const float*)d_in[1];
  const float* w_hh = (const float*)d_in[2];
  const float* b_ih = (const float*)d_in[3];
  const float* b_hh = (const float*)d_in[4];
  const float* w_fc = (const float*)d_in[5];
  const float* b_fc = (const float*)d_in[6];
  float* out = (float*)d_out;
  _Float16* hbuf = (_Float16*)((char*)d_ws + HB_OFF);

  hipLaunchKernelGGL(init_kernel, dim3(256), dim3(256), 0, stream, (int*)d_ws);
  hipLaunchKernelGGL(lstm_persist, dim3(512), dim3(512), 0, stream,
                     x, w_ih, w_hh, b_ih, b_hh, w_fc, b_fc, out, hbuf);
}